// Round 4
// baseline (311.079 us; speedup 1.0000x reference)
//
#include <hip/hip_runtime.h>
#include <cstddef>

#define C 128
#define TM 64
#define KP 32

// ---- fused 3x linear: h_j = x @ W[j] + b[j] ---------------------------
// grid (N/64, 3); block 256; thread = 8 rows x 4 cols.
// W streamed through LDS in 32-row double-buffered k-panels.
__global__ __launch_bounds__(256) void gemm3(
    const float* __restrict__ x, const float* __restrict__ W,
    const float* __restrict__ bias, float* __restrict__ out,
    float* __restrict__ h1, float* __restrict__ h2, int N) {
  __shared__ float xs[TM][C];        // 32 KB
  __shared__ float wbuf[2][KP * C];  // 2 x 16 KB
  const int j = blockIdx.y;
  const int row0 = blockIdx.x * TM;
  const int tid = threadIdx.x;

  // stage 64x128 x-tile (8 float4 per thread, coalesced)
#pragma unroll
  for (int it = 0; it < 8; ++it) {
    const int f = it * 256 + tid;       // float4 id 0..2047
    const int r = f >> 5;
    const int cq = (f & 31) << 2;
    const int gr = row0 + r;
    float4 v = make_float4(0.f, 0.f, 0.f, 0.f);
    if (gr < N) v = *reinterpret_cast<const float4*>(x + (size_t)gr * C + cq);
    *reinterpret_cast<float4*>(&xs[r][cq]) = v;
  }

  const float* __restrict__ Wj = W + (size_t)j * C * C;

  // prefetch k-panel 0 into regs (4 float4 per thread = 16 KB/block)
  float4 pw[4];
#pragma unroll
  for (int it = 0; it < 4; ++it)
    pw[it] = *reinterpret_cast<const float4*>(Wj + (size_t)(it * 256 + tid) * 4);

  const int tc4 = (tid & 31) << 2;   // col base
  const int r0 = (tid >> 5) << 3;    // row base

  float acc[8][4];
#pragma unroll
  for (int m = 0; m < 8; ++m)
#pragma unroll
    for (int q = 0; q < 4; ++q) acc[m][q] = 0.0f;

  for (int p = 0; p < 4; ++p) {
    float* wb = wbuf[p & 1];
    // write staged panel into LDS
#pragma unroll
    for (int it = 0; it < 4; ++it)
      *reinterpret_cast<float4*>(&wb[(it * 256 + tid) << 2]) = pw[it];
    __syncthreads();  // panel p visible; xs ready (p==0); buf free (see dbuf note)
    // issue next panel's global loads early (in flight under the FMAs)
    if (p < 3) {
      const float* src = Wj + (size_t)(p + 1) * KP * C;
#pragma unroll
      for (int it = 0; it < 4; ++it)
        pw[it] = *reinterpret_cast<const float4*>(src + (size_t)(it * 256 + tid) * 4);
    }
    // compute 32 k-steps from LDS only
#pragma unroll 4
    for (int kk = 0; kk < KP; kk += 2) {
      const float4 w0 = *reinterpret_cast<const float4*>(&wb[kk * C + tc4]);
      const float4 w1 = *reinterpret_cast<const float4*>(&wb[(kk + 1) * C + tc4]);
      const int kg = p * KP + kk;
#pragma unroll
      for (int m = 0; m < 8; ++m) {
        const float2 xv = *reinterpret_cast<const float2*>(&xs[r0 + m][kg]);
        acc[m][0] += xv.x * w0.x + xv.y * w1.x;
        acc[m][1] += xv.x * w0.y + xv.y * w1.y;
        acc[m][2] += xv.x * w0.z + xv.y * w1.z;
        acc[m][3] += xv.x * w0.w + xv.y * w1.w;
      }
    }
    // no bottom barrier: next iter writes the OTHER buffer, whose readers
    // all passed this iter's top barrier.
  }

  const float4 bv = *reinterpret_cast<const float4*>(bias + (size_t)j * C + tc4);
  float* base = (j == 0) ? out : ((j == 1) ? h1 : h2);
  const int stride = (j == 0) ? 384 : 128;
#pragma unroll
  for (int m = 0; m < 8; ++m) {
    const int gr = row0 + r0 + m;
    if (gr >= N) continue;
    float4 o;
    o.x = acc[m][0] + bv.x; o.y = acc[m][1] + bv.y;
    o.z = acc[m][2] + bv.z; o.w = acc[m][3] + bv.w;
    *reinterpret_cast<float4*>(base + (size_t)gr * stride + tc4) = o;
  }
}

// ---- CSR build --------------------------------------------------------
__global__ __launch_bounds__(256) void hist_rows(
    const int* __restrict__ row, int* __restrict__ cnt, int E) {
  int i = blockIdx.x * 256 + threadIdx.x;
  int stride = gridDim.x * 256;
  for (; i < E; i += stride) atomicAdd(&cnt[row[i]], 1);
}

__global__ __launch_bounds__(1024) void scan_local(
    const int* __restrict__ cnt, int* __restrict__ part,
    int* __restrict__ bsum, int N) {
  __shared__ int wsum[16];
  const int tid = threadIdx.x;
  const int i = blockIdx.x * 1024 + tid;
  const int v = (i < N) ? cnt[i] : 0;
  const int lane = tid & 63, w = tid >> 6;
  int s = v;
#pragma unroll
  for (int off = 1; off < 64; off <<= 1) {
    int t = __shfl_up(s, off, 64);
    if (lane >= off) s += t;
  }
  if (lane == 63) wsum[w] = s;
  __syncthreads();
  if (tid < 16) {
    int ws = wsum[tid];
#pragma unroll
    for (int off = 1; off < 16; off <<= 1) {
      int t = __shfl_up(ws, off, 16);
      if (tid >= off) ws += t;
    }
    wsum[tid] = ws;
  }
  __syncthreads();
  const int woff = w ? wsum[w - 1] : 0;
  if (i < N) part[i] = woff + s - v;
  if (tid == 0) bsum[blockIdx.x] = wsum[15];
}

__global__ __launch_bounds__(64) void scan_carry(
    const int* __restrict__ bsum, int* __restrict__ carry,
    int* __restrict__ row_ptr, int nb, int N) {
  const int tid = threadIdx.x;
  const int v = (tid < nb) ? bsum[tid] : 0;
  int s = v;
#pragma unroll
  for (int off = 1; off < 64; off <<= 1) {
    int t = __shfl_up(s, off, 64);
    if (tid >= off) s += t;
  }
  if (tid < nb) carry[tid] = s - v;
  if (tid == 63) row_ptr[N] = s;
}

__global__ __launch_bounds__(1024) void scan_apply(
    int* __restrict__ part, const int* __restrict__ carry,
    int* __restrict__ cursor, int N) {
  const int i = blockIdx.x * 1024 + threadIdx.x;
  if (i < N) {
    const int v = part[i] + carry[blockIdx.x];
    part[i] = v;
    cursor[i] = v;
  }
}

__global__ __launch_bounds__(256) void scatter_edges(
    const int* __restrict__ row, const int* __restrict__ col,
    const float* __restrict__ val, int* __restrict__ cursor,
    int2* __restrict__ ep, int E) {
  int i = blockIdx.x * 256 + threadIdx.x;
  int stride = gridDim.x * 256;
  for (; i < E; i += stride) {
    int r = row[i];
    int pos = atomicAdd(&cursor[r], 1);
    ep[pos] = make_int2(col[i], __float_as_int(val[i]));
  }
}

// ---- SpMM: one row per 64-lane wave, float2 per lane, 4-edge MLP ------
__global__ __launch_bounds__(256) void spmm_csr(
    const float* __restrict__ h, const int* __restrict__ rp,
    const int2* __restrict__ ep, float* __restrict__ outp,
    int N, int ostride) {
  const int r = blockIdx.x * 4 + (threadIdx.x >> 6);
  if (r >= N) return;
  const int c2 = (threadIdx.x & 63) << 1;
  const int s = rp[r];
  const int e = rp[r + 1];
  float2 a0 = make_float2(0.f, 0.f), a1 = a0, a2 = a0, a3 = a0;
  int i = s;
  for (; i + 3 < e; i += 4) {
    const int2 e0 = ep[i], e1 = ep[i + 1], e2 = ep[i + 2], e3 = ep[i + 3];
    const float2 g0 = *reinterpret_cast<const float2*>(h + (size_t)e0.x * C + c2);
    const float2 g1 = *reinterpret_cast<const float2*>(h + (size_t)e1.x * C + c2);
    const float2 g2 = *reinterpret_cast<const float2*>(h + (size_t)e2.x * C + c2);
    const float2 g3 = *reinterpret_cast<const float2*>(h + (size_t)e3.x * C + c2);
    const float v0 = __int_as_float(e0.y), v1 = __int_as_float(e1.y);
    const float v2 = __int_as_float(e2.y), v3 = __int_as_float(e3.y);
    a0.x += v0 * g0.x; a0.y += v0 * g0.y;
    a1.x += v1 * g1.x; a1.y += v1 * g1.y;
    a2.x += v2 * g2.x; a2.y += v2 * g2.y;
    a3.x += v3 * g3.x; a3.y += v3 * g3.y;
  }
  for (; i < e; ++i) {
    const int2 e0 = ep[i];
    const float v0 = __int_as_float(e0.y);
    const float2 g0 = *reinterpret_cast<const float2*>(h + (size_t)e0.x * C + c2);
    a0.x += v0 * g0.x; a0.y += v0 * g0.y;
  }
  float2 res;
  res.x = (a0.x + a1.x) + (a2.x + a3.x);
  res.y = (a0.y + a1.y) + (a2.y + a3.y);
  *reinterpret_cast<float2*>(outp + (size_t)r * ostride + c2) = res;
}

extern "C" void kernel_launch(void* const* d_in, const int* in_sizes, int n_in,
                              void* d_out, int out_size, void* d_ws, size_t ws_size,
                              hipStream_t stream) {
  const float* x  = (const float*)d_in[0];
  const float* W  = (const float*)d_in[1];
  const float* b  = (const float*)d_in[2];
  const float* ev = (const float*)d_in[3];
  const int*   er = (const int*)d_in[4];
  const int*   ec = (const int*)d_in[5];
  const int N = in_sizes[0] / C;
  const int E = in_sizes[3];
  float* out = (float*)d_out;

  const size_t NB = (size_t)N * C;
  char* ws = (char*)d_ws;
  float* h1      = (float*)ws;  ws += NB * sizeof(float);
  float* h2      = (float*)ws;  ws += NB * sizeof(float);
  int*   row_ptr = (int*)ws;    ws += (size_t)(N + 1) * sizeof(int);
  int*   cursor  = (int*)ws;    ws += (size_t)N * sizeof(int);
  int*   bsum    = (int*)ws;    ws += 64 * sizeof(int);
  int*   carry   = (int*)ws;    ws += 64 * sizeof(int);
  int2*  ep      = (int2*)ws;
  float* t = h1;  // h1 dead after hop-1 spmm (stream-serialized)

  const int nb = (N + 1023) / 1024;

  // CSR build (cursor doubles as the count buffer)
  hipMemsetAsync(cursor, 0, (size_t)N * sizeof(int), stream);
  const int eb0 = (E + 255) / 256;
  const int eblocks = eb0 < 2048 ? eb0 : 2048;
  hist_rows<<<eblocks, 256, 0, stream>>>(er, cursor, E);
  scan_local<<<nb, 1024, 0, stream>>>(cursor, row_ptr, bsum, N);
  scan_carry<<<1, 64, 0, stream>>>(bsum, carry, row_ptr, nb, N);
  scan_apply<<<nb, 1024, 0, stream>>>(row_ptr, carry, cursor, N);
  scatter_edges<<<eblocks, 256, 0, stream>>>(er, ec, ev, cursor, ep, E);

  // fused linears
  dim3 ggrid((N + TM - 1) / TM, 3);
  gemm3<<<ggrid, 256, 0, stream>>>(x, W, b, out, h1, h2, N);

  // SpMM passes
  const int sblocks = (N + 3) / 4;
  spmm_csr<<<sblocks, 256, 0, stream>>>(h1, row_ptr, ep, out + C, N, 3 * C);
  spmm_csr<<<sblocks, 256, 0, stream>>>(h2, row_ptr, ep, t, N, C);
  spmm_csr<<<sblocks, 256, 0, stream>>>(t, row_ptr, ep, out + 2 * C, N, 3 * C);
}